// Round 2
// baseline (916.079 us; speedup 1.0000x reference)
//
#include <hip/hip_runtime.h>
#include <hip/hip_bf16.h>
#include <stdint.h>

#define LOG2E 1.44269504088896340736f
#define LN2   0.69314718055994530942f

typedef __attribute__((ext_vector_type(8))) __bf16 bf16x8;
typedef __attribute__((ext_vector_type(4))) float  f32x4;

static constexpr int B = 128, S = 512, T = 256;
static constexpr int LDP = T + 8;   // padded LDS row (bf16 elems): +16B -> 4-bank rotate per row

static __device__ __forceinline__ uint pack_bf16x2(float a, float b) {
    __hip_bfloat162 h = __float22bfloat162_rn(make_float2(a, b));
    union { __hip_bfloat162 h; uint u; } cv; cv.h = h;
    return cv.u;
}
static __device__ __forceinline__ float bf2f(ushort u) {
    return __uint_as_float(((uint)u) << 16);
}

// ---------------- prep: Et[j][i] = bf16( exp2(trans[i][j] * LOG2E) ) ----------------
__global__ void prep_Et(const float* __restrict__ trans, ushort* __restrict__ Et) {
    int j = blockIdx.x;    // 256
    int i = threadIdx.x;   // 256
    float e = exp2f(trans[i * T + j] * LOG2E);
    uint u = __float_as_uint(e);
    Et[j * T + i] = (ushort)((u + 0x7FFFu + ((u >> 16) & 1u)) >> 16);  // RTNE
}

// ---------------- main scan: one WG per (scan, batch-group of 16) ----------------
// scan 0 = partition (mask ignored), scan 1 = score (mask-aware). Identical code
// path when mask==1 everywhere -> bitwise-identical results -> diff cancels exactly.
__launch_bounds__(256, 1)
__global__ void crf_scan(const float* __restrict__ em,      // [B][S][T]
                         const int* __restrict__ mask,      // [B][S] (bool -> int32 per harness)
                         const float* __restrict__ startt,  // [T]
                         const float* __restrict__ endt,    // [T]
                         const ushort* __restrict__ Et,     // [T][T] bf16, Et[j][i]=exp(trans[i][j])
                         float* __restrict__ res)           // [2][B] log2-domain results
{
    const int tid  = threadIdx.x;
    const int wave = tid >> 6;          // 0..3 : j-range [64*wave, 64*wave+64)
    const int lane = tid & 63;
    const int q    = lane >> 4;         // quad 0..3
    const int l    = lane & 15;         // local batch 0..15
    const int scan = blockIdx.x & 1;
    const int bg   = blockIdx.x >> 1;   // 0..7
    const int b    = bg * 16 + l;       // this lane's batch (column of MFMA tile)

    __shared__ __align__(16) ushort Al[2][16][LDP];   // alpha, bf16, double-buffered
    __shared__ float mxbuf[4][16];                    // per-wave per-batch max

    // ---- Load Et fragments (A-operand, step-invariant) into registers: 128 VGPRs/wave.
    // A[m = lane&15 -> state j][k = quad*8+jj -> i], contiguous i in Et[j][:].
    bf16x8 Afr[4][8];
    #pragma unroll
    for (int mt = 0; mt < 4; ++mt) {
        int j = wave * 64 + mt * 16 + l;
        #pragma unroll
        for (int kt = 0; kt < 8; ++kt) {
            Afr[mt][kt] = *reinterpret_cast<const bf16x8*>(&Et[j * T + kt * 32 + q * 8]);
        }
    }

    int ls = 0;   // per-batch log2 scale accumulator (exact integer)
    int buf = 0;

    // ---- init: alpha0 = exp2((start + em[:,0]) * LOG2E), renormalized
    {
        float v[4][4]; float mx = 0.0f;
        #pragma unroll
        for (int t = 0; t < 4; ++t) {
            int j0 = wave * 64 + t * 16 + q * 4;
            f32x4 e4 = *reinterpret_cast<const f32x4*>(&em[(size_t)b * S * T + j0]);
            f32x4 s4 = *reinterpret_cast<const f32x4*>(&startt[j0]);
            #pragma unroll
            for (int r = 0; r < 4; ++r) {
                v[t][r] = exp2f((e4[r] + s4[r]) * LOG2E);
                mx = fmaxf(mx, v[t][r]);
            }
        }
        mx = fmaxf(mx, __shfl_xor(mx, 16));
        mx = fmaxf(mx, __shfl_xor(mx, 32));
        if (q == 0) mxbuf[wave][l] = mx;
        __syncthreads();
        mx = fmaxf(fmaxf(mxbuf[0][l], mxbuf[1][l]), fmaxf(mxbuf[2][l], mxbuf[3][l]));
        int e = (int)((__float_as_uint(mx) >> 23) & 255u) - 127;
        float sc = __uint_as_float((uint)(127 - e) << 23);   // exact 2^-e
        ls += e;
        #pragma unroll
        for (int t = 0; t < 4; ++t) {
            int j0 = wave * 64 + t * 16 + q * 4;
            uint2 w;
            w.x = pack_bf16x2(v[t][0] * sc, v[t][1] * sc);
            w.y = pack_bf16x2(v[t][2] * sc, v[t][3] * sc);
            *reinterpret_cast<uint2*>(&Al[0][l][j0]) = w;
        }
        __syncthreads();
    }

    const int* mrow = mask + (size_t)b * S;

    for (int s = 1; s < S; ++s) {
        // prefetch em for this step at this lane's C-layout positions
        f32x4 e4[4];
        #pragma unroll
        for (int t = 0; t < 4; ++t) {
            int j0 = wave * 64 + t * 16 + q * 4;
            e4[t] = *reinterpret_cast<const f32x4*>(&em[(size_t)b * S * T + (size_t)s * T + j0]);
        }
        int mk = scan ? mrow[s] : 1;

        // P[j][b] = sum_i Et[j][i] * alpha[b][i]   (D = A*B, n = batch)
        f32x4 acc[4] = {f32x4{0,0,0,0}, f32x4{0,0,0,0}, f32x4{0,0,0,0}, f32x4{0,0,0,0}};
        #pragma unroll
        for (int kt = 0; kt < 8; ++kt) {
            bf16x8 bfr = *reinterpret_cast<const bf16x8*>(&Al[buf][l][kt * 32 + q * 8]);
            #pragma unroll
            for (int mt = 0; mt < 4; ++mt)
                acc[mt] = __builtin_amdgcn_mfma_f32_16x16x32_bf16(Afr[mt][kt], bfr, acc[mt], 0, 0, 0);
        }

        // epilogue: * exp(em), per-batch max, exact power-of-2 renorm, bf16 pack
        float v[4][4]; float mx = 0.0f;
        #pragma unroll
        for (int t = 0; t < 4; ++t) {
            #pragma unroll
            for (int r = 0; r < 4; ++r) {
                float x = acc[t][r] * exp2f(e4[t][r] * LOG2E);
                v[t][r] = x; mx = fmaxf(mx, x);
            }
        }
        mx = fmaxf(mx, __shfl_xor(mx, 16));
        mx = fmaxf(mx, __shfl_xor(mx, 32));
        if (q == 0) mxbuf[wave][l] = mx;
        __syncthreads();
        mx = fmaxf(fmaxf(mxbuf[0][l], mxbuf[1][l]), fmaxf(mxbuf[2][l], mxbuf[3][l]));
        int e = (int)((__float_as_uint(mx) >> 23) & 255u) - 127;
        float sc = __uint_as_float((uint)(127 - e) << 23);

        int nb = buf ^ 1;
        if (mk) {
            ls += e;
            #pragma unroll
            for (int t = 0; t < 4; ++t) {
                int j0 = wave * 64 + t * 16 + q * 4;
                uint2 w;
                w.x = pack_bf16x2(v[t][0] * sc, v[t][1] * sc);
                w.y = pack_bf16x2(v[t][2] * sc, v[t][3] * sc);
                *reinterpret_cast<uint2*>(&Al[nb][l][j0]) = w;
            }
        } else {
            // masked step: carry old alpha bits forward unchanged (score scan only)
            #pragma unroll
            for (int t = 0; t < 4; ++t) {
                int j0 = wave * 64 + t * 16 + q * 4;
                *reinterpret_cast<uint2*>(&Al[nb][l][j0]) =
                    *reinterpret_cast<const uint2*>(&Al[buf][l][j0]);
            }
        }
        buf = nb;
        __syncthreads();
    }

    // ---- final: res = ls + log2( sum_j alpha[b][j] * exp2(end[j]*LOG2E) )
    float part = 0.0f;
    #pragma unroll
    for (int kt = 0; kt < 8; ++kt) {
        int i0 = kt * 32 + q * 8;
        f32x4 ea = *reinterpret_cast<const f32x4*>(&endt[i0]);
        f32x4 eb = *reinterpret_cast<const f32x4*>(&endt[i0 + 4]);
        ushort4 a0 = *reinterpret_cast<const ushort4*>(&Al[buf][l][i0]);
        ushort4 a1 = *reinterpret_cast<const ushort4*>(&Al[buf][l][i0 + 4]);
        part += bf2f(a0.x) * exp2f(ea[0] * LOG2E);
        part += bf2f(a0.y) * exp2f(ea[1] * LOG2E);
        part += bf2f(a0.z) * exp2f(ea[2] * LOG2E);
        part += bf2f(a0.w) * exp2f(ea[3] * LOG2E);
        part += bf2f(a1.x) * exp2f(eb[0] * LOG2E);
        part += bf2f(a1.y) * exp2f(eb[1] * LOG2E);
        part += bf2f(a1.z) * exp2f(eb[2] * LOG2E);
        part += bf2f(a1.w) * exp2f(eb[3] * LOG2E);
    }
    part += __shfl_xor(part, 16);
    part += __shfl_xor(part, 32);   // each wave now holds the full sum over all i

    if (wave == 0 && q == 0) {
        res[scan * B + b] = (float)ls + log2f(part);
    }
}

// ---------------- combine: out[b] = (partition - score) * ln2 ----------------
__global__ void combine(const float* __restrict__ res, float* __restrict__ out) {
    int b = threadIdx.x;  // 128
    out[b] = (res[b] - res[B + b]) * LN2;
}

extern "C" void kernel_launch(void* const* d_in, const int* in_sizes, int n_in,
                              void* d_out, int out_size, void* d_ws, size_t ws_size,
                              hipStream_t stream) {
    (void)in_sizes; (void)n_in; (void)out_size; (void)ws_size;
    const float* em  = (const float*)d_in[0];
    const int*   mk  = (const int*)d_in[1];
    const float* st  = (const float*)d_in[2];
    const float* en  = (const float*)d_in[3];
    const float* tr  = (const float*)d_in[4];

    ushort* Et  = (ushort*)d_ws;                                   // 128 KiB
    float*  res = (float*)((char*)d_ws + (size_t)T * T * sizeof(ushort));  // 1 KiB

    prep_Et<<<T, T, 0, stream>>>(tr, Et);
    crf_scan<<<16, 256, 0, stream>>>(em, mk, st, en, Et, res);
    combine<<<1, B, 0, stream>>>(res, (float*)d_out);
}

// Round 3
// 719.334 us; speedup vs baseline: 1.2735x; 1.2735x over previous
//
#include <hip/hip_runtime.h>
#include <hip/hip_bf16.h>
#include <stdint.h>

#define LOG2E 1.44269504088896340736f
#define LN2   0.69314718055994530942f

typedef __attribute__((ext_vector_type(8))) __bf16 bf16x8;
typedef __attribute__((ext_vector_type(4))) float  f32x4;

static constexpr int B = 128, S = 512, T = 256;
static constexpr int LDP = T + 8;   // padded LDS row (bf16 elems)

static __device__ __forceinline__ uint pack_bf16x2(float a, float b) {
    __hip_bfloat162 h = __float22bfloat162_rn(make_float2(a, b));
    union { __hip_bfloat162 h; uint u; } cv; cv.h = h;
    return cv.u;
}
static __device__ __forceinline__ float bf2f(ushort u) {
    return __uint_as_float(((uint)u) << 16);
}

// ---------------- prep: Et[j][i] = bf16( exp(trans[i][j]) ) ----------------
__global__ void prep_Et(const float* __restrict__ trans, ushort* __restrict__ Et) {
    int j = blockIdx.x;    // 256
    int i = threadIdx.x;   // 256
    float e = exp2f(trans[i * T + j] * LOG2E);
    uint u = __float_as_uint(e);
    Et[j * T + i] = (ushort)((u + 0x7FFFu + ((u >> 16) & 1u)) >> 16);  // RTNE
}

// ---------------- prep: emx = bf16( exp(em) ), elementwise over B*S*T ----------------
__global__ void prep_emx(const float* __restrict__ em, ushort* __restrict__ emx) {
    size_t i4 = ((size_t)blockIdx.x * blockDim.x + threadIdx.x) * 4;
    f32x4 e = *reinterpret_cast<const f32x4*>(&em[i4]);
    uint2 w;
    w.x = pack_bf16x2(exp2f(e[0] * LOG2E), exp2f(e[1] * LOG2E));
    w.y = pack_bf16x2(exp2f(e[2] * LOG2E), exp2f(e[3] * LOG2E));
    *reinterpret_cast<uint2*>(&emx[i4]) = w;
}

// ---------------- main scan: one WG per (scan, batch-group of 16) ----------------
// Delayed renormalization: alpha stored UNSCALED in bf16 (bounded by one-step
// gain ~2^21); per-batch scale 2^-kappa applied in the NEXT step's epilogue,
// kappa = exponent of previous step's max (exchanged at the same barrier as
// alpha). One barrier per step. Both scans are instruction-identical when
// mask==1 -> bitwise-identical results -> partition - score == 0 exactly.
template<bool PRE>
__launch_bounds__(256, 1)
__global__ void crf_scan(const float* __restrict__ em,      // [B][S][T] fp32
                         const ushort* __restrict__ emx,    // [B][S][T] bf16 exp(em) (PRE)
                         const int* __restrict__ mask,      // [B][S] int32
                         const float* __restrict__ startt,  // [T]
                         const float* __restrict__ endt,    // [T]
                         const ushort* __restrict__ Et,     // [T][T] bf16, Et[j][i]=exp(trans[i][j])
                         float* __restrict__ res)           // [2][B] log2-domain results
{
    const int tid  = threadIdx.x;
    const int wave = tid >> 6;          // 0..3 : j-range [64*wave, 64*wave+64)
    const int lane = tid & 63;
    const int q    = lane >> 4;         // quad 0..3
    const int l    = lane & 15;         // local batch 0..15
    const int scan = blockIdx.x & 1;
    const int bg   = blockIdx.x >> 1;   // 0..7
    const int b    = bg * 16 + l;       // this lane's batch (MFMA N index)

    __shared__ __align__(16) ushort Al[2][16][LDP];   // alpha, bf16, double-buffered
    __shared__ float mxbuf[2][4][16];                 // per-wave per-batch max, dbuf

    // ---- Et fragments (A-operand, step-invariant): 128 VGPRs/wave.
    bf16x8 Afr[4][8];
    #pragma unroll
    for (int mt = 0; mt < 4; ++mt) {
        int j = wave * 64 + mt * 16 + l;
        #pragma unroll
        for (int kt = 0; kt < 8; ++kt)
            Afr[mt][kt] = *reinterpret_cast<const bf16x8*>(&Et[j * T + kt * 32 + q * 8]);
    }

    const float*  emrow = em  + (size_t)b * S * T;
    const ushort* exrow = PRE ? emx + (size_t)b * S * T : nullptr;
    const int*    mrow  = mask + (size_t)b * S;

    int ls = 0;     // per-batch log2 scale accumulator
    int buf = 0;

    // ---- init: alpha0 = exp2((start + em[:,0]) * LOG2E), fully normalized once
    {
        float v[4][4]; float mx = 0.0f;
        #pragma unroll
        for (int t = 0; t < 4; ++t) {
            int j0 = wave * 64 + t * 16 + q * 4;
            f32x4 e4 = *reinterpret_cast<const f32x4*>(&emrow[j0]);
            f32x4 s4 = *reinterpret_cast<const f32x4*>(&startt[j0]);
            #pragma unroll
            for (int r = 0; r < 4; ++r) {
                v[t][r] = exp2f((e4[r] + s4[r]) * LOG2E);
                mx = fmaxf(mx, v[t][r]);
            }
        }
        mx = fmaxf(mx, __shfl_xor(mx, 16));
        mx = fmaxf(mx, __shfl_xor(mx, 32));
        if (q == 0) mxbuf[0][wave][l] = mx;
        __syncthreads();
        float gmx = fmaxf(fmaxf(mxbuf[0][0][l], mxbuf[0][1][l]),
                          fmaxf(mxbuf[0][2][l], mxbuf[0][3][l]));
        int e = (int)((__float_as_uint(gmx) >> 23) & 255u) - 127;
        float sc = __uint_as_float((uint)(127 - e) << 23);   // exact 2^-e
        ls = e;
        #pragma unroll
        for (int t = 0; t < 4; ++t) {
            int j0 = wave * 64 + t * 16 + q * 4;
            uint2 w;
            w.x = pack_bf16x2(v[t][0] * sc, v[t][1] * sc);
            w.y = pack_bf16x2(v[t][2] * sc, v[t][3] * sc);
            *reinterpret_cast<uint2*>(&Al[0][l][j0]) = w;
        }
        __syncthreads();
        if (q == 0) mxbuf[0][wave][l] = mx * sc;   // max of stored alpha0
        __syncthreads();
    }

    // ---- prefetch step s=1 em (+mask) into registers
    uint2  exv[4];   // PRE: bf16 exp(em)
    f32x4  emv[4];   // !PRE: raw em
    #pragma unroll
    for (int t = 0; t < 4; ++t) {
        int j0 = wave * 64 + t * 16 + q * 4;
        if (PRE) exv[t] = *reinterpret_cast<const uint2*>(&exrow[(size_t)1 * T + j0]);
        else     emv[t] = *reinterpret_cast<const f32x4*>(&emrow[(size_t)1 * T + j0]);
    }
    int mkv = scan ? mrow[1] : 1;

    for (int s = 1; s < S; ++s) {
        const int nb = buf ^ 1;

        // ---- kappa from previous step's maxes (independent of MFMA)
        float gmx = fmaxf(fmaxf(mxbuf[buf][0][l], mxbuf[buf][1][l]),
                          fmaxf(mxbuf[buf][2][l], mxbuf[buf][3][l]));
        int   kap  = (int)((__float_as_uint(gmx) >> 23) & 255u) - 127;
        float sc   = __uint_as_float((uint)(127 - kap) << 23);   // exact 2^-kap
        float kapf = (float)kap;

        // ---- prefetch next step's em (+mask)
        uint2 exn[4]; f32x4 emn[4];
        if (s + 1 < S) {
            #pragma unroll
            for (int t = 0; t < 4; ++t) {
                int j0 = wave * 64 + t * 16 + q * 4;
                if (PRE) exn[t] = *reinterpret_cast<const uint2*>(&exrow[(size_t)(s + 1) * T + j0]);
                else     emn[t] = *reinterpret_cast<const f32x4*>(&emrow[(size_t)(s + 1) * T + j0]);
            }
        }
        int mkn = (scan && s + 1 < S) ? mrow[s + 1] : 1;

        // ---- MFMA: P[j][b] = sum_i Et[j][i] * alpha_stored[b][i]
        f32x4 acc[4] = {f32x4{0,0,0,0}, f32x4{0,0,0,0}, f32x4{0,0,0,0}, f32x4{0,0,0,0}};
        #pragma unroll
        for (int kt = 0; kt < 8; ++kt) {
            bf16x8 bfr = *reinterpret_cast<const bf16x8*>(&Al[buf][l][kt * 32 + q * 8]);
            #pragma unroll
            for (int mt = 0; mt < 4; ++mt)
                acc[mt] = __builtin_amdgcn_mfma_f32_16x16x32_bf16(Afr[mt][kt], bfr, acc[mt], 0, 0, 0);
        }

        // ---- epilogue: v = acc * exp(em) * 2^-kap (unscaled store, delayed norm)
        const int mk = mkv;
        float v[4][4];
        #pragma unroll
        for (int t = 0; t < 4; ++t) {
            if (PRE) {
                v[t][0] = acc[t][0] * bf2f((ushort)(exv[t].x & 0xFFFF)) * sc;
                v[t][1] = acc[t][1] * bf2f((ushort)(exv[t].x >> 16))    * sc;
                v[t][2] = acc[t][2] * bf2f((ushort)(exv[t].y & 0xFFFF)) * sc;
                v[t][3] = acc[t][3] * bf2f((ushort)(exv[t].y >> 16))    * sc;
            } else {
                #pragma unroll
                for (int r = 0; r < 4; ++r)
                    v[t][r] = acc[t][r] * exp2f(emv[t][r] * LOG2E - kapf);
            }
        }

        // write alpha (new buffer) first so ds_writes drain during max calc
        if (mk) {
            #pragma unroll
            for (int t = 0; t < 4; ++t) {
                int j0 = wave * 64 + t * 16 + q * 4;
                uint2 w;
                w.x = pack_bf16x2(v[t][0], v[t][1]);
                w.y = pack_bf16x2(v[t][2], v[t][3]);
                *reinterpret_cast<uint2*>(&Al[nb][l][j0]) = w;
            }
            ls += kap;
        } else {
            #pragma unroll
            for (int t = 0; t < 4; ++t) {
                int j0 = wave * 64 + t * 16 + q * 4;
                *reinterpret_cast<uint2*>(&Al[nb][l][j0]) =
                    *reinterpret_cast<const uint2*>(&Al[buf][l][j0]);
            }
        }

        // per-wave per-batch max of stored values (for next step's kappa)
        float mx = 0.0f;
        #pragma unroll
        for (int t = 0; t < 4; ++t)
            #pragma unroll
            for (int r = 0; r < 4; ++r) mx = fmaxf(mx, v[t][r]);
        mx = fmaxf(mx, __shfl_xor(mx, 16));
        mx = fmaxf(mx, __shfl_xor(mx, 32));
        if (q == 0) mxbuf[nb][wave][l] = mk ? mx : mxbuf[buf][wave][l];

        __syncthreads();
        buf = nb;
        #pragma unroll
        for (int t = 0; t < 4; ++t) { exv[t] = exn[t]; emv[t] = emn[t]; }
        mkv = mkn;
    }

    // ---- final: res = ls + log2( sum_j alpha_stored[b][j] * exp(end[j]) )
    float part = 0.0f;
    #pragma unroll
    for (int kt = 0; kt < 8; ++kt) {
        int i0 = kt * 32 + q * 8;
        f32x4 ea = *reinterpret_cast<const f32x4*>(&endt[i0]);
        f32x4 eb = *reinterpret_cast<const f32x4*>(&endt[i0 + 4]);
        ushort4 a0 = *reinterpret_cast<const ushort4*>(&Al[buf][l][i0]);
        ushort4 a1 = *reinterpret_cast<const ushort4*>(&Al[buf][l][i0 + 4]);
        part += bf2f(a0.x) * exp2f(ea[0] * LOG2E);
        part += bf2f(a0.y) * exp2f(ea[1] * LOG2E);
        part += bf2f(a0.z) * exp2f(ea[2] * LOG2E);
        part += bf2f(a0.w) * exp2f(ea[3] * LOG2E);
        part += bf2f(a1.x) * exp2f(eb[0] * LOG2E);
        part += bf2f(a1.y) * exp2f(eb[1] * LOG2E);
        part += bf2f(a1.z) * exp2f(eb[2] * LOG2E);
        part += bf2f(a1.w) * exp2f(eb[3] * LOG2E);
    }
    part += __shfl_xor(part, 16);
    part += __shfl_xor(part, 32);

    if (wave == 0 && q == 0)
        res[scan * B + b] = (float)ls + log2f(part);
}

// ---------------- combine: out[b] = (partition - score) * ln2 ----------------
__global__ void combine(const float* __restrict__ res, float* __restrict__ out) {
    int b = threadIdx.x;  // 128
    out[b] = (res[b] - res[B + b]) * LN2;
}

extern "C" void kernel_launch(void* const* d_in, const int* in_sizes, int n_in,
                              void* d_out, int out_size, void* d_ws, size_t ws_size,
                              hipStream_t stream) {
    (void)in_sizes; (void)n_in; (void)out_size;
    const float* em = (const float*)d_in[0];
    const int*   mk = (const int*)d_in[1];
    const float* st = (const float*)d_in[2];
    const float* en = (const float*)d_in[3];
    const float* tr = (const float*)d_in[4];

    ushort* Et  = (ushort*)d_ws;                              // 128 KiB
    float*  res = (float*)((char*)d_ws + (128 << 10));        // 1 KiB
    ushort* emx = (ushort*)((char*)d_ws + (256 << 10));       // 32 MiB (optional)

    const size_t emx_bytes = (size_t)B * S * T * sizeof(ushort);
    const bool pre = ws_size >= (256 << 10) + emx_bytes;

    prep_Et<<<T, T, 0, stream>>>(tr, Et);
    if (pre) {
        prep_emx<<<(B * S * T) / (256 * 4), 256, 0, stream>>>(em, emx);
        crf_scan<true><<<16, 256, 0, stream>>>(em, emx, mk, st, en, Et, res);
    } else {
        crf_scan<false><<<16, 256, 0, stream>>>(em, emx, mk, st, en, Et, res);
    }
    combine<<<1, B, 0, stream>>>(res, (float*)d_out);
}